// Round 1
// baseline (553.726 us; speedup 1.0000x reference)
//
#include <hip/hip_runtime.h>
#include <math.h>

// Problem constants (BATCH=1, so x is [SEQ][DM] flat).
#define SEQ   3072
#define DM    1024
#define NH    16
#define DH    64
#define WIN   128
#define DIL   4
#define TSUB  768      // SEQ / DIL, length of each phase sub-sequence

// ---------------------------------------------------------------------------
// GEMM body: C[M][N] = A[M][K] @ W[N][K]^T + bias[N], optionally scaled by
// 1/(sqrt(DH)*exp(beta[col/64])) for the Q projection.
// Tile 128x128, BK=8, 256 threads, 8x8 per-thread microtile. fp32 (no fp32
// MFMA on CDNA4; this is VALU-bound by design this round).
// ---------------------------------------------------------------------------
__device__ __forceinline__ void gemm_body(const float* __restrict__ A,
                                          const float* __restrict__ W,
                                          const float* __restrict__ bias,
                                          const float* __restrict__ beta, // null unless Q
                                          float* __restrict__ C,
                                          int bx, int by)
{
    __shared__ float As[8][128];   // As[k][m] (A tile transposed)
    __shared__ float Bs[8][128];   // Bs[k][n] (W tile transposed)
    const int K = DM;
    const int tid = threadIdx.x;
    const int lr = tid >> 1;          // 0..127 row within tile
    const int lc = (tid & 1) * 4;     // k offset 0 or 4
    const float* Ap = A + (size_t)(by * 128 + lr) * K + lc;
    const float* Wp = W + (size_t)(bx * 128 + lr) * K + lc;
    const int tx = tid & 15, ty = tid >> 4;

    float acc[8][8];
#pragma unroll
    for (int i = 0; i < 8; ++i)
#pragma unroll
        for (int j = 0; j < 8; ++j) acc[i][j] = 0.f;

    for (int k0 = 0; k0 < K; k0 += 8) {
        float4 av = *(const float4*)(Ap + k0);
        float4 wv = *(const float4*)(Wp + k0);
        __syncthreads();
        As[lc + 0][lr] = av.x; As[lc + 1][lr] = av.y;
        As[lc + 2][lr] = av.z; As[lc + 3][lr] = av.w;
        Bs[lc + 0][lr] = wv.x; Bs[lc + 1][lr] = wv.y;
        Bs[lc + 2][lr] = wv.z; Bs[lc + 3][lr] = wv.w;
        __syncthreads();
#pragma unroll
        for (int kk = 0; kk < 8; ++kk) {
            float a[8], b[8];
            *(float4*)&a[0] = *(const float4*)&As[kk][ty * 4];
            *(float4*)&a[4] = *(const float4*)&As[kk][64 + ty * 4];
            *(float4*)&b[0] = *(const float4*)&Bs[kk][tx * 4];
            *(float4*)&b[4] = *(const float4*)&Bs[kk][64 + tx * 4];
#pragma unroll
            for (int i = 0; i < 8; ++i)
#pragma unroll
                for (int j = 0; j < 8; ++j)
                    acc[i][j] = fmaf(a[i], b[j], acc[i][j]);
        }
    }

#pragma unroll
    for (int i = 0; i < 8; ++i) {
        int row = by * 128 + ((i < 4) ? (ty * 4 + i) : (64 + ty * 4 + i - 4));
        float* Crow = C + (size_t)row * DM;
#pragma unroll
        for (int jv = 0; jv < 2; ++jv) {
            int col = bx * 128 + ((jv == 0) ? (tx * 4) : (64 + tx * 4));
            float scale = 1.0f;
            if (beta) scale = 0.125f * __expf(-beta[col >> 6]);  // 1/(sqrt(64)*e^beta)
            float4 r4;
            r4.x = (acc[i][jv * 4 + 0] + bias[col + 0]) * scale;
            r4.y = (acc[i][jv * 4 + 1] + bias[col + 1]) * scale;
            r4.z = (acc[i][jv * 4 + 2] + bias[col + 2]) * scale;
            r4.w = (acc[i][jv * 4 + 3] + bias[col + 3]) * scale;
            *(float4*)(Crow + col) = r4;
        }
    }
}

// Fused QKV projection: grid (8, 24, 3); z selects q/k/v.
__global__ __launch_bounds__(256) void qkv_kernel(
    const float* __restrict__ x,
    const float* __restrict__ Wq, const float* __restrict__ bq,
    const float* __restrict__ Wk, const float* __restrict__ bk,
    const float* __restrict__ Wv, const float* __restrict__ bv,
    const float* __restrict__ beta,
    float* __restrict__ q, float* __restrict__ k, float* __restrict__ v)
{
    const int z = blockIdx.z;
    const float* W = (z == 0) ? Wq : (z == 1) ? Wk : Wv;
    const float* b = (z == 0) ? bq : (z == 1) ? bk : bv;
    float* C       = (z == 0) ? q  : (z == 1) ? k  : v;
    gemm_body(x, W, b, (z == 0) ? beta : nullptr, C, blockIdx.x, blockIdx.y);
}

// Output projection: grid (8, 24).
__global__ __launch_bounds__(256) void out_kernel(
    const float* __restrict__ ctx, const float* __restrict__ Wo,
    const float* __restrict__ bo, float* __restrict__ out)
{
    gemm_body(ctx, Wo, bo, nullptr, out, blockIdx.x, blockIdx.y);
}

// ---------------------------------------------------------------------------
// Attention. Dilation=4 => 4 independent phase sub-sequences (t = i/4,
// r = i%4), each a plain causal sliding window of 128 in t-space.
// Block = 256 threads handles (head h, phase r, 32 queries t0..t0+31).
// Key slots ks=0..191 map to t' = t0 - 160 + ks (covers [t_q-127, t_q] for
// all 32 queries). All scores kept in LDS -> one exact softmax, no online
// rescaling.
// ---------------------------------------------------------------------------
__global__ __launch_bounds__(256) void attn_kernel(
    const float* __restrict__ q, const float* __restrict__ k,
    const float* __restrict__ v, float* __restrict__ ctx)
{
    __shared__ float Qs[32][64];     // [query][dim]            8 KB
    __shared__ float KV[64][68];     // K: [dim][key] / V: [key][dim]  17.4 KB
    __shared__ float S[32][192];     // scores/probs            24 KB
    __shared__ float Rsum[32];

    const int tid = threadIdx.x;
    const int t0  = blockIdx.x * 32;   // query tile base in t-space
    const int r   = blockIdx.y;        // phase
    const int h   = blockIdx.z;        // head
    const int hoff = h * DH;

    // ---- load Q tile (32 x 64 floats) ----
    for (int l = tid; l < 32 * 16; l += 256) {
        int qi = l >> 4, dq = (l & 15) * 4;
        int i = 4 * (t0 + qi) + r;
        *(float4*)&Qs[qi][dq] = *(const float4*)&q[(size_t)i * DM + hoff + dq];
    }

    const int sq = tid >> 3;           // 0..31 query row owned in score/PV phases
    const int kg = (tid & 7) * 8;      // key group base (scores)
    const int t_q = t0 + sq;

    // ---- scores: 3 chunks of 64 keys ----
    for (int c = 0; c < 3; ++c) {
        int tbase = t0 - 160 + c * 64;
        {   // stage K chunk transposed: KV[d][key]
            int kk = tid >> 2;
            int d0 = (tid & 3) * 16;
            int tp = tbase + kk;
            if (tp >= 0 && tp < TSUB) {
                const float* kp = &k[(size_t)(4 * tp + r) * DM + hoff + d0];
#pragma unroll
                for (int u = 0; u < 16; u += 4) {
                    float4 kv4 = *(const float4*)(kp + u);
                    KV[d0 + u + 0][kk] = kv4.x; KV[d0 + u + 1][kk] = kv4.y;
                    KV[d0 + u + 2][kk] = kv4.z; KV[d0 + u + 3][kk] = kv4.w;
                }
            } else {
#pragma unroll
                for (int u = 0; u < 16; ++u) KV[d0 + u][kk] = 0.f;
            }
        }
        __syncthreads();

        float sc[8];
#pragma unroll
        for (int u = 0; u < 8; ++u) sc[u] = 0.f;
#pragma unroll 4
        for (int d = 0; d < 64; ++d) {
            float qv = Qs[sq][d];
            float4 ka = *(const float4*)&KV[d][kg];
            float4 kb = *(const float4*)&KV[d][kg + 4];
            sc[0] = fmaf(qv, ka.x, sc[0]); sc[1] = fmaf(qv, ka.y, sc[1]);
            sc[2] = fmaf(qv, ka.z, sc[2]); sc[3] = fmaf(qv, ka.w, sc[3]);
            sc[4] = fmaf(qv, kb.x, sc[4]); sc[5] = fmaf(qv, kb.y, sc[5]);
            sc[6] = fmaf(qv, kb.z, sc[6]); sc[7] = fmaf(qv, kb.w, sc[7]);
        }
#pragma unroll
        for (int u = 0; u < 8; ++u) {
            int ks = c * 64 + kg + u;
            int tp = tbase + kg + u;
            bool ok = (tp >= 0) && (tp <= t_q) && (tp >= t_q - (WIN - 1));
            S[sq][ks] = ok ? sc[u] : -1e30f;
        }
        __syncthreads();   // KV reused next chunk
    }

    // ---- softmax: 8 threads per query row, 24 slots each ----
    {
        const int part = tid & 7;
        float m = -1e30f;
        for (int ks = part * 24; ks < part * 24 + 24; ++ks)
            m = fmaxf(m, S[sq][ks]);
#pragma unroll
        for (int o = 1; o < 8; o <<= 1) m = fmaxf(m, __shfl_xor(m, o));
        float sum = 0.f;
        for (int ks = part * 24; ks < part * 24 + 24; ++ks) {
            float e = __expf(S[sq][ks] - m);
            S[sq][ks] = e;
            sum += e;
        }
#pragma unroll
        for (int o = 1; o < 8; o <<= 1) sum += __shfl_xor(sum, o);
        if (part == 0) Rsum[sq] = 1.0f / sum;
    }

    // ---- PV: thread owns (query sq, dims d0..d0+7) ----
    const int d0 = (tid & 7) * 8;
    float ov[8];
#pragma unroll
    for (int u = 0; u < 8; ++u) ov[u] = 0.f;

    for (int c = 0; c < 3; ++c) {
        int tbase = t0 - 160 + c * 64;
        {   // stage V chunk natural: KV[key][dim]
            int kk = tid >> 2;
            int dd = (tid & 3) * 16;
            int tp = tbase + kk;
            if (tp >= 0 && tp < TSUB) {
                const float* vp = &v[(size_t)(4 * tp + r) * DM + hoff + dd];
#pragma unroll
                for (int u = 0; u < 16; u += 4)
                    *(float4*)&KV[kk][dd + u] = *(const float4*)(vp + u);
            } else {
                float4 z4 = {0.f, 0.f, 0.f, 0.f};
#pragma unroll
                for (int u = 0; u < 16; u += 4) *(float4*)&KV[kk][dd + u] = z4;
            }
        }
        __syncthreads();   // also orders softmax S-writes before S-reads below
#pragma unroll 4
        for (int kk = 0; kk < 64; ++kk) {
            float p = S[sq][c * 64 + kk];
            float4 v0 = *(const float4*)&KV[kk][d0];
            float4 v1 = *(const float4*)&KV[kk][d0 + 4];
            ov[0] = fmaf(p, v0.x, ov[0]); ov[1] = fmaf(p, v0.y, ov[1]);
            ov[2] = fmaf(p, v0.z, ov[2]); ov[3] = fmaf(p, v0.w, ov[3]);
            ov[4] = fmaf(p, v1.x, ov[4]); ov[5] = fmaf(p, v1.y, ov[5]);
            ov[6] = fmaf(p, v1.z, ov[6]); ov[7] = fmaf(p, v1.w, ov[7]);
        }
        __syncthreads();   // KV reused next chunk
    }

    const float rs = Rsum[sq];
    const size_t row = (size_t)(4 * t_q + r);
    float4 o0, o1;
    o0.x = ov[0] * rs; o0.y = ov[1] * rs; o0.z = ov[2] * rs; o0.w = ov[3] * rs;
    o1.x = ov[4] * rs; o1.y = ov[5] * rs; o1.z = ov[6] * rs; o1.w = ov[7] * rs;
    *(float4*)&ctx[row * DM + hoff + d0]     = o0;
    *(float4*)&ctx[row * DM + hoff + d0 + 4] = o1;
}

// ---------------------------------------------------------------------------
// Inputs (setup_inputs order): x, beta, Wq, bq, Wk, bk, Wv, bv, Wo, bo.
// Workspace: q, k, v, ctx -> 4 * 3072*1024*4 B = 50.3 MB (assumed <= ws_size).
// ---------------------------------------------------------------------------
extern "C" void kernel_launch(void* const* d_in, const int* in_sizes, int n_in,
                              void* d_out, int out_size, void* d_ws, size_t ws_size,
                              hipStream_t stream)
{
    const float* x    = (const float*)d_in[0];
    const float* beta = (const float*)d_in[1];
    const float* Wq   = (const float*)d_in[2];
    const float* bq   = (const float*)d_in[3];
    const float* Wk   = (const float*)d_in[4];
    const float* bk   = (const float*)d_in[5];
    const float* Wv   = (const float*)d_in[6];
    const float* bv   = (const float*)d_in[7];
    const float* Wo   = (const float*)d_in[8];
    const float* bo   = (const float*)d_in[9];

    float* q   = (float*)d_ws;
    float* k   = q + (size_t)SEQ * DM;
    float* v   = k + (size_t)SEQ * DM;
    float* ctx = v + (size_t)SEQ * DM;
    float* out = (float*)d_out;

    dim3 gqkv(DM / 128, SEQ / 128, 3);          // (8, 24, 3)
    qkv_kernel<<<gqkv, 256, 0, stream>>>(x, Wq, bq, Wk, bk, Wv, bv, beta, q, k, v);

    dim3 gattn(TSUB / 32, DIL, NH);             // (24, 4, 16)
    attn_kernel<<<gattn, 256, 0, stream>>>(q, k, v, ctx);

    dim3 gout(DM / 128, SEQ / 128);             // (8, 24)
    out_kernel<<<gout, 256, 0, stream>>>(ctx, Wo, bo, out);
}

// Round 2
// 226.687 us; speedup vs baseline: 2.4427x; 2.4427x over previous
//
#include <hip/hip_runtime.h>
#include <math.h>

#define SEQ   3072
#define DM    1024
#define NH    16
#define DH    64
#define WIN   128
#define DIL   4
#define TSUB  768      // SEQ / DIL

typedef __attribute__((ext_vector_type(8))) short  short8;   // 8 bf16 (4 VGPRs)
typedef __attribute__((ext_vector_type(4))) float  floatx4;  // MFMA C/D

__device__ __forceinline__ float bf2f(unsigned short u) {
    return __uint_as_float(((unsigned)u) << 16);
}
__device__ __forceinline__ float bflo(unsigned u) { return __uint_as_float(u << 16); }
__device__ __forceinline__ float bfhi(unsigned u) { return __uint_as_float(u & 0xffff0000u); }
__device__ __forceinline__ unsigned short f2bf(float f) {   // RNE, finite inputs
    unsigned u = __float_as_uint(f);
    return (unsigned short)((u + 0x7FFFu + ((u >> 16) & 1u)) >> 16);
}

// async global->LDS, 16B/lane; LDS dest is wave-uniform base + lane*16.
__device__ __forceinline__ void gload_lds16(const void* g, void* l) {
    __builtin_amdgcn_global_load_lds(
        (const __attribute__((address_space(1))) void*)g,
        (__attribute__((address_space(3))) void*)l, 16, 0, 0);
}

// ---------------------------------------------------------------------------
// fp32 -> bf16 conversion for x and the four weight matrices. grid=(3072,5).
// ---------------------------------------------------------------------------
__global__ __launch_bounds__(256) void convert_kernel(
    const float* __restrict__ x,  const float* __restrict__ Wq,
    const float* __restrict__ Wk, const float* __restrict__ Wv,
    const float* __restrict__ Wo,
    ushort* __restrict__ xb,  ushort* __restrict__ Wqb,
    ushort* __restrict__ Wkb, ushort* __restrict__ Wvb,
    ushort* __restrict__ Wob)
{
    const float* s; ushort* d; int n;
    switch (blockIdx.y) {
        case 0: s = x;  d = xb;  n = SEQ * DM; break;
        case 1: s = Wq; d = Wqb; n = DM * DM;  break;
        case 2: s = Wk; d = Wkb; n = DM * DM;  break;
        case 3: s = Wv; d = Wvb; n = DM * DM;  break;
        default: s = Wo; d = Wob; n = DM * DM; break;
    }
    int i = (blockIdx.x * 256 + threadIdx.x) * 4;
    if (i >= n) return;
    float4 v = *(const float4*)&s[i];
    ushort4 o = { f2bf(v.x), f2bf(v.y), f2bf(v.z), f2bf(v.w) };
    *(ushort4*)&d[i] = o;
}

// ---------------------------------------------------------------------------
// bf16 MFMA GEMM: C[M][N] = A[M][K] @ W[N][K]^T + bias (+ optional Q scale).
// 128x128x32 tile, 256 thr = 4 waves (2x2), each wave 4x4 MFMAs of 16x16x32.
// A,W bf16 K-major; LDS tiles unpadded (global_load_lds requires contiguity).
// Fragment layouts (HW-verified, guide §3): A/B lane holds [m|n=lane&15]
// [k=(lane>>4)*8 + j]; C/D: col=lane&15, row=(lane>>4)*4+reg.
// ---------------------------------------------------------------------------
template<bool BF16OUT, bool QSCALE>
__device__ __forceinline__ void mfma_gemm(const ushort* __restrict__ A,
                                          const ushort* __restrict__ W,
                                          const float* __restrict__ bias,
                                          const float* __restrict__ beta,
                                          void* __restrict__ Cv,
                                          int bx, int by)
{
    __shared__ ushort As[128][32];   // [m][k] 8 KB
    __shared__ ushort Bs[128][32];   // [n][k] 8 KB

    const int tid  = threadIdx.x;
    const int lane = tid & 63, w = tid >> 6;
    const int ln15 = lane & 15, quad = lane >> 4;
    const int wm = w >> 1, wn = w & 1;

    // staging: wave w fills rows 32w..32w+31 of each tile; lane -> (row=l/4, k=(l%4)*8)
    const ushort* aP0 = A + (size_t)(by * 128 + 32 * w + (lane >> 2)) * DM + (lane & 3) * 8;
    const ushort* aP1 = aP0 + 16 * DM;
    const ushort* bP0 = W + (size_t)(bx * 128 + 32 * w + (lane >> 2)) * DM + (lane & 3) * 8;
    const ushort* bP1 = bP0 + 16 * DM;
    ushort* lA0 = &As[32 * w][0];
    ushort* lA1 = &As[32 * w + 16][0];
    ushort* lB0 = &Bs[32 * w][0];
    ushort* lB1 = &Bs[32 * w + 16][0];

    const floatx4 zero = {0.f, 0.f, 0.f, 0.f};
    floatx4 acc[4][4];
#pragma unroll
    for (int i = 0; i < 4; ++i)
#pragma unroll
        for (int j = 0; j < 4; ++j) acc[i][j] = zero;

    for (int k0 = 0; k0 < DM; k0 += 32) {
        __syncthreads();                 // previous iter's LDS reads done
        gload_lds16(aP0, lA0);
        gload_lds16(aP1, lA1);
        gload_lds16(bP0, lB0);
        gload_lds16(bP1, lB1);
        aP0 += 32; aP1 += 32; bP0 += 32; bP1 += 32;
        __syncthreads();                 // drains vmcnt before barrier

        short8 af[4], bf[4];
#pragma unroll
        for (int i = 0; i < 4; ++i)
            af[i] = *(const short8*)&As[wm * 64 + i * 16 + ln15][quad * 8];
#pragma unroll
        for (int j = 0; j < 4; ++j)
            bf[j] = *(const short8*)&Bs[wn * 64 + j * 16 + ln15][quad * 8];
#pragma unroll
        for (int i = 0; i < 4; ++i)
#pragma unroll
            for (int j = 0; j < 4; ++j)
                acc[i][j] = __builtin_amdgcn_mfma_f32_16x16x32_bf16(af[i], bf[j], acc[i][j], 0, 0, 0);
    }

#pragma unroll
    for (int j = 0; j < 4; ++j) {
        const int col = bx * 128 + wn * 64 + j * 16 + ln15;
        const float b = bias[col];
        const float scale = QSCALE ? 0.125f * __expf(-beta[col >> 6]) : 1.0f;
#pragma unroll
        for (int i = 0; i < 4; ++i) {
            const int row0 = by * 128 + wm * 64 + i * 16 + quad * 4;
#pragma unroll
            for (int rg = 0; rg < 4; ++rg) {
                float vv = (acc[i][j][rg] + b) * scale;
                if (BF16OUT)
                    ((ushort*)Cv)[(size_t)(row0 + rg) * DM + col] = f2bf(vv);
                else
                    ((float*)Cv)[(size_t)(row0 + rg) * DM + col] = vv;
            }
        }
    }
}

// grid (8, 24, 3): z selects Q/K/V.
__global__ __launch_bounds__(256) void qkv_kernel(
    const ushort* __restrict__ xb,
    const ushort* __restrict__ Wqb, const float* __restrict__ bq,
    const ushort* __restrict__ Wkb, const float* __restrict__ bk,
    const ushort* __restrict__ Wvb, const float* __restrict__ bv,
    const float* __restrict__ beta,
    ushort* __restrict__ q, ushort* __restrict__ k, ushort* __restrict__ v)
{
    const int z = blockIdx.z;
    const ushort* W = (z == 0) ? Wqb : (z == 1) ? Wkb : Wvb;
    const float*  b = (z == 0) ? bq  : (z == 1) ? bk  : bv;
    ushort*       C = (z == 0) ? q   : (z == 1) ? k   : v;
    if (z == 0)
        mfma_gemm<true, true >(xb, W, b, beta, C, blockIdx.x, blockIdx.y);
    else
        mfma_gemm<true, false>(xb, W, b, nullptr, C, blockIdx.x, blockIdx.y);
}

// grid (8, 24): out = ctx @ Wo^T + bo, fp32 output.
__global__ __launch_bounds__(256) void out_kernel(
    const ushort* __restrict__ ctxb, const ushort* __restrict__ Wob,
    const float* __restrict__ bo, float* __restrict__ out)
{
    mfma_gemm<false, false>(ctxb, Wob, bo, nullptr, out, blockIdx.x, blockIdx.y);
}

// ---------------------------------------------------------------------------
// Attention (fp32 compute, bf16 I/O). Dilation phases are independent causal
// windows of 128 in t-space. Block=(head, phase, 32-query tile); scores for
// all 192 reachable key slots kept in LDS -> one exact softmax.
// ---------------------------------------------------------------------------
__global__ __launch_bounds__(256) void attn_kernel(
    const ushort* __restrict__ q, const ushort* __restrict__ k,
    const ushort* __restrict__ v, ushort* __restrict__ ctx)
{
    __shared__ float Qs[32][64];
    __shared__ float KV[64][68];
    __shared__ float S[32][192];
    __shared__ float Rsum[32];

    const int tid = threadIdx.x;
    const int t0  = blockIdx.x * 32;
    const int r   = blockIdx.y;
    const int h   = blockIdx.z;
    const int hoff = h * DH;

    // ---- Q tile (32 x 64) ----
    for (int l = tid; l < 32 * 16; l += 256) {
        int qi = l >> 4, dq = (l & 15) * 4;
        int i = 4 * (t0 + qi) + r;
        ushort4 t = *(const ushort4*)&q[(size_t)i * DM + hoff + dq];
        Qs[qi][dq + 0] = bf2f(t.x); Qs[qi][dq + 1] = bf2f(t.y);
        Qs[qi][dq + 2] = bf2f(t.z); Qs[qi][dq + 3] = bf2f(t.w);
    }

    const int sq = tid >> 3;
    const int kg = (tid & 7) * 8;
    const int t_q = t0 + sq;

    // ---- scores: 3 chunks of 64 keys ----
    for (int c = 0; c < 3; ++c) {
        int tbase = t0 - 160 + c * 64;
        {   // stage K transposed: KV[d][key]
            int kk = tid >> 2;
            int d0 = (tid & 3) * 16;
            int tp = tbase + kk;
            if (tp >= 0 && tp < TSUB) {
                const ushort* kp = &k[(size_t)(4 * tp + r) * DM + hoff + d0];
                uint4 p0 = *(const uint4*)kp;
                uint4 p1 = *(const uint4*)(kp + 8);
                KV[d0 +  0][kk] = bflo(p0.x); KV[d0 +  1][kk] = bfhi(p0.x);
                KV[d0 +  2][kk] = bflo(p0.y); KV[d0 +  3][kk] = bfhi(p0.y);
                KV[d0 +  4][kk] = bflo(p0.z); KV[d0 +  5][kk] = bfhi(p0.z);
                KV[d0 +  6][kk] = bflo(p0.w); KV[d0 +  7][kk] = bfhi(p0.w);
                KV[d0 +  8][kk] = bflo(p1.x); KV[d0 +  9][kk] = bfhi(p1.x);
                KV[d0 + 10][kk] = bflo(p1.y); KV[d0 + 11][kk] = bfhi(p1.y);
                KV[d0 + 12][kk] = bflo(p1.z); KV[d0 + 13][kk] = bfhi(p1.z);
                KV[d0 + 14][kk] = bflo(p1.w); KV[d0 + 15][kk] = bfhi(p1.w);
            } else {
#pragma unroll
                for (int u = 0; u < 16; ++u) KV[d0 + u][kk] = 0.f;
            }
        }
        __syncthreads();

        float sc[8];
#pragma unroll
        for (int u = 0; u < 8; ++u) sc[u] = 0.f;
#pragma unroll 4
        for (int d = 0; d < 64; ++d) {
            float qv = Qs[sq][d];
            float4 ka = *(const float4*)&KV[d][kg];
            float4 kb = *(const float4*)&KV[d][kg + 4];
            sc[0] = fmaf(qv, ka.x, sc[0]); sc[1] = fmaf(qv, ka.y, sc[1]);
            sc[2] = fmaf(qv, ka.z, sc[2]); sc[3] = fmaf(qv, ka.w, sc[3]);
            sc[4] = fmaf(qv, kb.x, sc[4]); sc[5] = fmaf(qv, kb.y, sc[5]);
            sc[6] = fmaf(qv, kb.z, sc[6]); sc[7] = fmaf(qv, kb.w, sc[7]);
        }
#pragma unroll
        for (int u = 0; u < 8; ++u) {
            int ks = c * 64 + kg + u;
            int tp = tbase + kg + u;
            bool ok = (tp >= 0) && (tp <= t_q) && (tp >= t_q - (WIN - 1));
            S[sq][ks] = ok ? sc[u] : -1e30f;
        }
        __syncthreads();
    }

    // ---- softmax: 8 threads/row, 24 slots each ----
    {
        const int part = tid & 7;
        float m = -1e30f;
        for (int ks = part * 24; ks < part * 24 + 24; ++ks)
            m = fmaxf(m, S[sq][ks]);
#pragma unroll
        for (int o = 1; o < 8; o <<= 1) m = fmaxf(m, __shfl_xor(m, o));
        float sum = 0.f;
        for (int ks = part * 24; ks < part * 24 + 24; ++ks) {
            float e = __expf(S[sq][ks] - m);
            S[sq][ks] = e;
            sum += e;
        }
#pragma unroll
        for (int o = 1; o < 8; o <<= 1) sum += __shfl_xor(sum, o);
        if (part == 0) Rsum[sq] = 1.0f / sum;
    }

    // ---- PV ----
    const int d0 = (tid & 7) * 8;
    float ov[8];
#pragma unroll
    for (int u = 0; u < 8; ++u) ov[u] = 0.f;

    for (int c = 0; c < 3; ++c) {
        int tbase = t0 - 160 + c * 64;
        {   // stage V natural: KV[key][dim]
            int kk = tid >> 2;
            int dd = (tid & 3) * 16;
            int tp = tbase + kk;
            if (tp >= 0 && tp < TSUB) {
                const ushort* vp = &v[(size_t)(4 * tp + r) * DM + hoff + dd];
                uint4 p0 = *(const uint4*)vp;
                uint4 p1 = *(const uint4*)(vp + 8);
                float4 f0 = {bflo(p0.x), bfhi(p0.x), bflo(p0.y), bfhi(p0.y)};
                float4 f1 = {bflo(p0.z), bfhi(p0.z), bflo(p0.w), bfhi(p0.w)};
                float4 f2 = {bflo(p1.x), bfhi(p1.x), bflo(p1.y), bfhi(p1.y)};
                float4 f3 = {bflo(p1.z), bfhi(p1.z), bflo(p1.w), bfhi(p1.w)};
                *(float4*)&KV[kk][dd + 0]  = f0;
                *(float4*)&KV[kk][dd + 4]  = f1;
                *(float4*)&KV[kk][dd + 8]  = f2;
                *(float4*)&KV[kk][dd + 12] = f3;
            } else {
                float4 z4 = {0.f, 0.f, 0.f, 0.f};
#pragma unroll
                for (int u = 0; u < 16; u += 4) *(float4*)&KV[kk][dd + u] = z4;
            }
        }
        __syncthreads();
#pragma unroll 4
        for (int kk = 0; kk < 64; ++kk) {
            float p = S[sq][c * 64 + kk];
            float4 v0 = *(const float4*)&KV[kk][d0];
            float4 v1 = *(const float4*)&KV[kk][d0 + 4];
            ov[0] = fmaf(p, v0.x, ov[0]); ov[1] = fmaf(p, v0.y, ov[1]);
            ov[2] = fmaf(p, v0.z, ov[2]); ov[3] = fmaf(p, v0.w, ov[3]);
            ov[4] = fmaf(p, v1.x, ov[4]); ov[5] = fmaf(p, v1.y, ov[5]);
            ov[6] = fmaf(p, v1.z, ov[6]); ov[7] = fmaf(p, v1.w, ov[7]);
        }
        __syncthreads();
    }

    const float rs = Rsum[sq];
    const size_t row = (size_t)(4 * t_q + r);
    ushort4 o0 = { f2bf(ov[0] * rs), f2bf(ov[1] * rs), f2bf(ov[2] * rs), f2bf(ov[3] * rs) };
    ushort4 o1 = { f2bf(ov[4] * rs), f2bf(ov[5] * rs), f2bf(ov[6] * rs), f2bf(ov[7] * rs) };
    *(ushort4*)&ctx[row * DM + hoff + d0]     = o0;
    *(ushort4*)&ctx[row * DM + hoff + d0 + 4] = o1;
}

// ---------------------------------------------------------------------------
// ws layout (all bf16): q, k, v, ctx (SEQ*DM each), x, Wq, Wk, Wv, Wo.
// Total ~39.8 MB (round-1 proved ws >= 50.3 MB).
// ---------------------------------------------------------------------------
extern "C" void kernel_launch(void* const* d_in, const int* in_sizes, int n_in,
                              void* d_out, int out_size, void* d_ws, size_t ws_size,
                              hipStream_t stream)
{
    const float* x    = (const float*)d_in[0];
    const float* beta = (const float*)d_in[1];
    const float* Wq   = (const float*)d_in[2];
    const float* bq   = (const float*)d_in[3];
    const float* Wk   = (const float*)d_in[4];
    const float* bk   = (const float*)d_in[5];
    const float* Wv   = (const float*)d_in[6];
    const float* bv   = (const float*)d_in[7];
    const float* Wo   = (const float*)d_in[8];
    const float* bo   = (const float*)d_in[9];

    ushort* qb   = (ushort*)d_ws;
    ushort* kb   = qb   + (size_t)SEQ * DM;
    ushort* vb   = kb   + (size_t)SEQ * DM;
    ushort* ctxb = vb   + (size_t)SEQ * DM;
    ushort* xb   = ctxb + (size_t)SEQ * DM;
    ushort* Wqb  = xb   + (size_t)SEQ * DM;
    ushort* Wkb  = Wqb  + (size_t)DM * DM;
    ushort* Wvb  = Wkb  + (size_t)DM * DM;
    ushort* Wob  = Wvb  + (size_t)DM * DM;
    float*  out  = (float*)d_out;

    dim3 gcv(SEQ * DM / 4 / 256, 5);
    convert_kernel<<<gcv, 256, 0, stream>>>(x, Wq, Wk, Wv, Wo, xb, Wqb, Wkb, Wvb, Wob);

    dim3 gqkv(DM / 128, SEQ / 128, 3);
    qkv_kernel<<<gqkv, 256, 0, stream>>>(xb, Wqb, bq, Wkb, bk, Wvb, bv, beta, qb, kb, vb);

    dim3 gattn(TSUB / 32, DIL, NH);
    attn_kernel<<<gattn, 256, 0, stream>>>(qb, kb, vb, ctxb);

    dim3 gout(DM / 128, SEQ / 128);
    out_kernel<<<gout, 256, 0, stream>>>(ctxb, Wob, bo, out);
}

// Round 3
// 187.886 us; speedup vs baseline: 2.9471x; 1.2065x over previous
//
#include <hip/hip_runtime.h>
#include <math.h>

#define SEQ   3072
#define DM    1024
#define NH    16
#define DH    64
#define WIN   128
#define DIL   4
#define TSUB  768      // SEQ / DIL

typedef __attribute__((ext_vector_type(8))) short    short8;   // 8 bf16
typedef __attribute__((ext_vector_type(8))) _Float16 half8;    // 8 fp16
typedef __attribute__((ext_vector_type(4))) float    floatx4;  // MFMA C/D

__device__ __forceinline__ float bf2f(unsigned short u) {
    return __uint_as_float(((unsigned)u) << 16);
}
__device__ __forceinline__ unsigned short f2bf(float f) {   // RNE, finite inputs
    unsigned u = __float_as_uint(f);
    return (unsigned short)((u + 0x7FFFu + ((u >> 16) & 1u)) >> 16);
}
__device__ __forceinline__ unsigned short f2h(float f) {
    _Float16 h = (_Float16)f;
    return __builtin_bit_cast(unsigned short, h);
}

// async global->LDS, 16B/lane; HW places lane i at ldsbase + i*16.
__device__ __forceinline__ void gload_lds16(const void* g, void* l) {
    __builtin_amdgcn_global_load_lds(
        (const __attribute__((address_space(1))) void*)g,
        (__attribute__((address_space(3))) void*)l, 16, 0, 0);
}

// ---------------------------------------------------------------------------
// fp32 -> bf16 conversion for x and the four weight matrices. grid=(3072,5).
// ---------------------------------------------------------------------------
__global__ __launch_bounds__(256) void convert_kernel(
    const float* __restrict__ x,  const float* __restrict__ Wq,
    const float* __restrict__ Wk, const float* __restrict__ Wv,
    const float* __restrict__ Wo,
    ushort* __restrict__ xb,  ushort* __restrict__ Wqb,
    ushort* __restrict__ Wkb, ushort* __restrict__ Wvb,
    ushort* __restrict__ Wob)
{
    const float* s; ushort* d; int n;
    switch (blockIdx.y) {
        case 0: s = x;  d = xb;  n = SEQ * DM; break;
        case 1: s = Wq; d = Wqb; n = DM * DM;  break;
        case 2: s = Wk; d = Wkb; n = DM * DM;  break;
        case 3: s = Wv; d = Wvb; n = DM * DM;  break;
        default: s = Wo; d = Wob; n = DM * DM; break;
    }
    int i = (blockIdx.x * 256 + threadIdx.x) * 4;
    if (i >= n) return;
    float4 v = *(const float4*)&s[i];
    ushort4 o = { f2bf(v.x), f2bf(v.y), f2bf(v.z), f2bf(v.w) };
    *(ushort4*)&d[i] = o;
}

// ---------------------------------------------------------------------------
// bf16 MFMA GEMM (m97 structure): C = A @ W^T + bias (+ optional Q scale).
// 128x128x32 tile, 4 waves, 4x4 16x16x32 MFMAs per wave. Unchanged from R2.
// ---------------------------------------------------------------------------
template<bool BF16OUT, bool QSCALE>
__device__ __forceinline__ void mfma_gemm(const ushort* __restrict__ A,
                                          const ushort* __restrict__ W,
                                          const float* __restrict__ bias,
                                          const float* __restrict__ beta,
                                          void* __restrict__ Cv,
                                          int bx, int by)
{
    __shared__ ushort As[128][32];
    __shared__ ushort Bs[128][32];

    const int tid  = threadIdx.x;
    const int lane = tid & 63, w = tid >> 6;
    const int ln15 = lane & 15, quad = lane >> 4;
    const int wm = w >> 1, wn = w & 1;

    const ushort* aP0 = A + (size_t)(by * 128 + 32 * w + (lane >> 2)) * DM + (lane & 3) * 8;
    const ushort* aP1 = aP0 + 16 * DM;
    const ushort* bP0 = W + (size_t)(bx * 128 + 32 * w + (lane >> 2)) * DM + (lane & 3) * 8;
    const ushort* bP1 = bP0 + 16 * DM;
    ushort* lA0 = &As[32 * w][0];
    ushort* lA1 = &As[32 * w + 16][0];
    ushort* lB0 = &Bs[32 * w][0];
    ushort* lB1 = &Bs[32 * w + 16][0];

    const floatx4 zero = {0.f, 0.f, 0.f, 0.f};
    floatx4 acc[4][4];
#pragma unroll
    for (int i = 0; i < 4; ++i)
#pragma unroll
        for (int j = 0; j < 4; ++j) acc[i][j] = zero;

    for (int k0 = 0; k0 < DM; k0 += 32) {
        __syncthreads();
        gload_lds16(aP0, lA0);
        gload_lds16(aP1, lA1);
        gload_lds16(bP0, lB0);
        gload_lds16(bP1, lB1);
        aP0 += 32; aP1 += 32; bP0 += 32; bP1 += 32;
        __syncthreads();

        short8 af[4], bf[4];
#pragma unroll
        for (int i = 0; i < 4; ++i)
            af[i] = *(const short8*)&As[wm * 64 + i * 16 + ln15][quad * 8];
#pragma unroll
        for (int j = 0; j < 4; ++j)
            bf[j] = *(const short8*)&Bs[wn * 64 + j * 16 + ln15][quad * 8];
#pragma unroll
        for (int i = 0; i < 4; ++i)
#pragma unroll
            for (int j = 0; j < 4; ++j)
                acc[i][j] = __builtin_amdgcn_mfma_f32_16x16x32_bf16(af[i], bf[j], acc[i][j], 0, 0, 0);
    }

#pragma unroll
    for (int j = 0; j < 4; ++j) {
        const int col = bx * 128 + wn * 64 + j * 16 + ln15;
        const float b = bias[col];
        const float scale = QSCALE ? 0.125f * __expf(-beta[col >> 6]) : 1.0f;
#pragma unroll
        for (int i = 0; i < 4; ++i) {
            const int row0 = by * 128 + wm * 64 + i * 16 + quad * 4;
#pragma unroll
            for (int rg = 0; rg < 4; ++rg) {
                float vv = (acc[i][j][rg] + b) * scale;
                if (BF16OUT)
                    ((ushort*)Cv)[(size_t)(row0 + rg) * DM + col] = f2bf(vv);
                else
                    ((float*)Cv)[(size_t)(row0 + rg) * DM + col] = vv;
            }
        }
    }
}

__global__ __launch_bounds__(256) void qkv_kernel(
    const ushort* __restrict__ xb,
    const ushort* __restrict__ Wqb, const float* __restrict__ bq,
    const ushort* __restrict__ Wkb, const float* __restrict__ bk,
    const ushort* __restrict__ Wvb, const float* __restrict__ bv,
    const float* __restrict__ beta,
    ushort* __restrict__ q, ushort* __restrict__ k, ushort* __restrict__ v)
{
    const int z = blockIdx.z;
    const ushort* W = (z == 0) ? Wqb : (z == 1) ? Wkb : Wvb;
    const float*  b = (z == 0) ? bq  : (z == 1) ? bk  : bv;
    ushort*       C = (z == 0) ? q   : (z == 1) ? k   : v;
    if (z == 0)
        mfma_gemm<true, true >(xb, W, b, beta, C, blockIdx.x, blockIdx.y);
    else
        mfma_gemm<true, false>(xb, W, b, nullptr, C, blockIdx.x, blockIdx.y);
}

__global__ __launch_bounds__(256) void out_kernel(
    const ushort* __restrict__ ctxb, const ushort* __restrict__ Wob,
    const float* __restrict__ bo, float* __restrict__ out)
{
    mfma_gemm<false, false>(ctxb, Wob, bo, nullptr, out, blockIdx.x, blockIdx.y);
}

// ---------------------------------------------------------------------------
// MFMA attention. Block = (32-query t-tile, phase r, head h), 4 waves.
//  - QK^T: bf16 MFMA. K staged via global_load_lds into [key][dg] rows of
//    128B where the dim-group is XOR-swizzled ON THE GLOBAL SIDE
//    (dg ^= key&7) -> unpadded LDS, conflict-free b128 frag reads.
//    Q A-frags load directly from global (no LDS).
//  - Halo slots (t' < 0) read into the q-buffer: valid, finite bf16 garbage,
//    masked to -1e30 before softmax. No zero-fill, no branches.
//  - Softmax: exact (192 slots in LDS, stride 195 -> <=2-way banks).
//  - PV: fp16 MFMA. V transposed once into frag-linear LDS (lane-linear 16B
//    chunks -> 2-way-free b128 reads); P read from S (fp32) and packed fp16.
// LDS: 24KB (Ks/Vt union) + 25KB S = 49.2KB -> 3 blocks/CU.
// ---------------------------------------------------------------------------
struct AttnSmem {
    union {
        ushort Ks[192 * 64];        // [key][dg] ; dg holds dims 8*(dg^(key&7))
        ushort Vt[6 * 4 * 64 * 8];  // [kc][dt][lane][8] fp16, lane-linear
    } u;
    float S[32][195];
    float Rsum[32];
};

__global__ __launch_bounds__(256) void attn_kernel(
    const ushort* __restrict__ q, const ushort* __restrict__ k,
    const ushort* __restrict__ v, ushort* __restrict__ ctx)
{
    __shared__ AttnSmem sm;

    const int tid  = threadIdx.x;
    const int lane = tid & 63, w = tid >> 6;
    const int ln15 = lane & 15, quad = lane >> 4;
    const int t0   = blockIdx.x * 32;
    const int r    = blockIdx.y;
    const int h    = blockIdx.z;
    const int hoff = h * DH;

    // ---- stage K (192 keys x 64 dims) via glds, 6 ops/wave -----------------
    {
        const int kr = lane >> 3;                   // key-in-op 0..7
        const int swz = ((lane & 7) ^ kr) * 8;      // XOR swizzle on global dim
#pragma unroll
        for (int ci = w * 6; ci < w * 6 + 6; ++ci) {
            int key = ci * 8 + kr;
            long grow = 4L * (t0 - 160 + key) + r;  // may be negative -> q buffer
            gload_lds16(k + grow * DM + hoff + swz, &sm.u.Ks[ci * 512]);
        }
    }

    // ---- Q A-frags direct from global (wave w owns qtile w>>1) -------------
    const int qt = w >> 1;
    short8 qf0, qf1;
    {
        int qrow = qt * 16 + ln15;
        const ushort* gq = q + (4L * (t0 + qrow) + r) * DM + hoff + quad * 8;
        qf0 = *(const short8*)gq;
        qf1 = *(const short8*)(gq + 32);
    }

    // ---- V loads into registers (writes to LDS deferred past barrier 2) ----
    short8 vreg[6];
#pragma unroll
    for (int it = 0; it < 6; ++it) {
        int idx = it * 256 + tid;                   // 0..1535
        int key = idx >> 3, d0 = (idx & 7) * 8;
        long grow = 4L * (t0 - 160 + key) + r;
        vreg[it] = *(const short8*)(v + grow * DM + hoff + d0);
    }

    __syncthreads();   // barrier 1: Ks staged (vmcnt drained by sync)

    // ---- QK^T: wave w -> qtile w>>1, ktiles (w&1)*6 .. +5 ------------------
    {
        const floatx4 zero = {0.f, 0.f, 0.f, 0.f};
        const int kt0 = (w & 1) * 6;
        const int lb  = ln15 & 7;
#pragma unroll
        for (int kk2 = 0; kk2 < 6; ++kk2) {
            const int kt  = kt0 + kk2;
            const int key = kt * 16 + ln15;
            short8 b0 = *(const short8*)&sm.u.Ks[key * 64 + ((quad ^ lb) << 3)];
            short8 b1 = *(const short8*)&sm.u.Ks[key * 64 + (((4 + quad) ^ lb) << 3)];
            floatx4 acc = zero;
            acc = __builtin_amdgcn_mfma_f32_16x16x32_bf16(qf0, b0, acc, 0, 0, 0);
            acc = __builtin_amdgcn_mfma_f32_16x16x32_bf16(qf1, b1, acc, 0, 0, 0);
            const int tp = t0 - 160 + key;          // key slot time
#pragma unroll
            for (int rg = 0; rg < 4; ++rg) {
                int qrow = qt * 16 + quad * 4 + rg;
                int tq = t0 + qrow;
                bool ok = (tp >= 0) && (tp <= tq) && (tp > tq - WIN);
                sm.S[qrow][key] = ok ? acc[rg] : -1e30f;
            }
        }
    }

    __syncthreads();   // barrier 2: S complete, Ks reads done (Vt may alias)

    // ---- V transpose -> frag-linear fp16 LDS -------------------------------
#pragma unroll
    for (int it = 0; it < 6; ++it) {
        int idx = it * 256 + tid;
        int key = idx >> 3, d0 = (idx & 7) * 8;
        int kc = key >> 5, qd = (key >> 3) & 3, jj = key & 7;
        short8 sv = vreg[it];
#pragma unroll
        for (int u = 0; u < 8; ++u) {
            int dim = d0 + u, dt = dim >> 4, ln = dim & 15;
            sm.u.Vt[(kc * 4 + dt) * 512 + (qd * 16 + ln) * 8 + jj] =
                f2h(bf2f((unsigned short)sv[u]));
        }
    }

    // ---- softmax: 8 threads/row, stride-8 slot ownership -------------------
    {
        const int sq = tid >> 3, part = tid & 7;
        float m = -1e30f;
#pragma unroll
        for (int j = 0; j < 24; ++j) m = fmaxf(m, sm.S[sq][part + 8 * j]);
#pragma unroll
        for (int o = 1; o < 8; o <<= 1) m = fmaxf(m, __shfl_xor(m, o));
        float sum = 0.f;
#pragma unroll
        for (int j = 0; j < 24; ++j) {
            int ks = part + 8 * j;
            float e = __expf(sm.S[sq][ks] - m);
            sm.S[sq][ks] = e;
            sum += e;
        }
#pragma unroll
        for (int o = 1; o < 8; o <<= 1) sum += __shfl_xor(sum, o);
        if (part == 0) sm.Rsum[sq] = 1.0f / sum;
    }

    __syncthreads();   // barrier 3: Vt + P(S) + Rsum ready

    // ---- PV: wave w -> qtile w&1, dtiles (w>>1)*2 .. +1 --------------------
    {
        const floatx4 zero = {0.f, 0.f, 0.f, 0.f};
        const int qtp = w & 1, dh = w >> 1;
        floatx4 o0 = zero, o1 = zero;
#pragma unroll
        for (int kc = 0; kc < 6; ++kc) {
            const float* ps = &sm.S[qtp * 16 + ln15][kc * 32 + quad * 8];
            half8 pa;
#pragma unroll
            for (int u = 0; u < 8; ++u) pa[u] = (_Float16)ps[u];
            half8 vb0 = *(const half8*)&sm.u.Vt[(kc * 4 + dh * 2 + 0) * 512 + lane * 8];
            half8 vb1 = *(const half8*)&sm.u.Vt[(kc * 4 + dh * 2 + 1) * 512 + lane * 8];
            o0 = __builtin_amdgcn_mfma_f32_16x16x32_f16(pa, vb0, o0, 0, 0, 0);
            o1 = __builtin_amdgcn_mfma_f32_16x16x32_f16(pa, vb1, o1, 0, 0, 0);
        }
#pragma unroll
        for (int rg = 0; rg < 4; ++rg) {
            int qrow = qtp * 16 + quad * 4 + rg;
            float rs = sm.Rsum[qrow];
            long orow = 4L * (t0 + qrow) + r;
            ushort* cp = ctx + orow * DM + hoff + dh * 32 + ln15;
            cp[0]  = f2bf(o0[rg] * rs);
            cp[16] = f2bf(o1[rg] * rs);
        }
    }
}

// ---------------------------------------------------------------------------
// ws layout (all bf16): q, k, v, ctx (SEQ*DM each), x, Wq, Wk, Wv, Wo.
// ---------------------------------------------------------------------------
extern "C" void kernel_launch(void* const* d_in, const int* in_sizes, int n_in,
                              void* d_out, int out_size, void* d_ws, size_t ws_size,
                              hipStream_t stream)
{
    const float* x    = (const float*)d_in[0];
    const float* beta = (const float*)d_in[1];
    const float* Wq   = (const float*)d_in[2];
    const float* bq   = (const float*)d_in[3];
    const float* Wk   = (const float*)d_in[4];
    const float* bk   = (const float*)d_in[5];
    const float* Wv   = (const float*)d_in[6];
    const float* bv   = (const float*)d_in[7];
    const float* Wo   = (const float*)d_in[8];
    const float* bo   = (const float*)d_in[9];

    ushort* qb   = (ushort*)d_ws;
    ushort* kb   = qb   + (size_t)SEQ * DM;
    ushort* vb   = kb   + (size_t)SEQ * DM;
    ushort* ctxb = vb   + (size_t)SEQ * DM;
    ushort* xb   = ctxb + (size_t)SEQ * DM;
    ushort* Wqb  = xb   + (size_t)SEQ * DM;
    ushort* Wkb  = Wqb  + (size_t)DM * DM;
    ushort* Wvb  = Wkb  + (size_t)DM * DM;
    ushort* Wob  = Wvb  + (size_t)DM * DM;
    float*  out  = (float*)d_out;

    dim3 gcv(SEQ * DM / 4 / 256, 5);
    convert_kernel<<<gcv, 256, 0, stream>>>(x, Wq, Wk, Wv, Wo, xb, Wqb, Wkb, Wvb, Wob);

    dim3 gqkv(DM / 128, SEQ / 128, 3);
    qkv_kernel<<<gqkv, 256, 0, stream>>>(xb, Wqb, bq, Wkb, bk, Wvb, bv, beta, qb, kb, vb);

    dim3 gattn(TSUB / 32, DIL, NH);
    attn_kernel<<<gattn, 256, 0, stream>>>(qb, kb, vb, ctxb);

    dim3 gout(DM / 128, SEQ / 128);
    out_kernel<<<gout, 256, 0, stream>>>(ctxb, Wob, bo, out);
}